// Round 4
// baseline (151.078 us; speedup 1.0000x reference)
//
#include <hip/hip_runtime.h>
#include <hip/hip_bf16.h>

// Problem constants (from reference setup_inputs)
#define N_PARENT 50000
#define C_IN     256
#define C_OUT    256
#define FANOUT   8
#define N_TGT    200000
#define N_UP     (N_PARENT * FANOUT)   // 400000 upsampled rows
#define NCOL     (FANOUT * C_OUT)      // 2048 = fused (k,d) GEMM-N
#define NSTRIP   391                   // ceil(50000/128) M-strips of 128 rows
#define NROWS    (NSTRIP * 128)        // 50048 (rows 50000..50047 are zero pad)

// Workspace layout (~27.1 MB)
//  A strips: bf16 [strip][t=0..7][8KB], 391*64KB   (t = 32-col K-step)
//  B tiles:  bf16 [bn][t=0..7][8KB], 16*64KB = 1MB
// Within an 8KB (128 rows x 32 cols bf16) block:
//   byte = r*64 + ((ch ^ (r&3))<<4) + lo   where ch = 16B chunk (8 bf16), lo<16
#define OFF_A    0u
#define OFF_B    (NSTRIP * 65536u)              // 25,624,576
#define OFF_V    (OFF_B + 16u * 65536u)         // float V[8][256]
#define OFF_EB   (OFF_V + 8192u)                // float ebias
#define OFF_KEEP (OFF_EB + 256u)                // uint8 keep[N_UP]

typedef __attribute__((ext_vector_type(8))) short short8;
typedef __attribute__((ext_vector_type(4))) float floatx4;

static __device__ __forceinline__ unsigned short f2bf(float f) {
    return __builtin_bit_cast(unsigned short, __float2bfloat16(f));
}

static __device__ __forceinline__ void gload_lds16(const void* gsrc, void* ldsdst) {
    __builtin_amdgcn_global_load_lds(
        (const __attribute__((address_space(1))) unsigned int*)gsrc,
        (__attribute__((address_space(3))) unsigned int*)ldsdst, 16, 0, 0);
}

// ---------------------------------------------------------------------------
// Kernel 1: build swizzled bf16 B tiles + V[k][c] = W_up[k] @ W_cls + ebias,
//           and zero the target output (fused zero pass).
// Grid: 2048 blocks (= k*256 + c), 256 threads (= d). Reads coalesced over d.
// ---------------------------------------------------------------------------
__global__ __launch_bounds__(256) void prep_kernel(
        const float* __restrict__ W_up, const float* __restrict__ b_up,
        const float* __restrict__ W_cls, const float* __restrict__ b_cls,
        unsigned char* __restrict__ ws, float* __restrict__ out2) {
    __shared__ float sm[4];
    const int bid = blockIdx.x;
    const int k = bid >> 8, c = bid & 255;
    const int d = threadIdx.x;

    // fused zero of out2 (100000 float4 across 2048 blocks, 49 each)
    if (d < 49) {
        const int i4 = bid * 49 + d;
        if (i4 < N_UP / 4)
            *(floatx4*)&out2[i4 * 4] = (floatx4){0.f, 0.f, 0.f, 0.f};
    }

    const float w = W_up[((k * 256 + c) * 256) + d];      // coalesced over d
    // B^T element: row j = k*256+d -> (bn = j>>7, jr = j&127), col c
    const int bn = (k << 1) | (d >> 7);
    const int jr = d & 127;
    const int t  = c >> 5;
    const int ch = (c >> 3) & 3;
    const int e  = c & 7;
    const unsigned off = OFF_B + (unsigned)bn * 65536u + (unsigned)t * 8192u
                       + (unsigned)jr * 64u + (unsigned)((ch ^ (jr & 3)) << 4)
                       + (unsigned)(e << 1);
    *(unsigned short*)(ws + off) = f2bf(w);

    // V[k][c] = sum_d w * W_cls[d]  (fp32 tree reduce)
    float p = w * W_cls[d];
    #pragma unroll
    for (int m = 1; m < 64; m <<= 1) p += __shfl_xor(p, m);
    if ((d & 63) == 0) sm[d >> 6] = p;
    __syncthreads();
    if (d == 0)
        ((float*)(ws + OFF_V))[k * 256 + c] = sm[0] + sm[1] + sm[2] + sm[3];

    if (bid == 0) {   // uniform branch: whole block participates
        __syncthreads();
        float q = b_up[d] * W_cls[d];
        #pragma unroll
        for (int m = 1; m < 64; m <<= 1) q += __shfl_xor(q, m);
        if ((d & 63) == 0) sm[d >> 6] = q;
        __syncthreads();
        if (d == 0)
            *((float*)(ws + OFF_EB)) = sm[0] + sm[1] + sm[2] + sm[3] + b_cls[0];
    }
}

// ---------------------------------------------------------------------------
// Kernel 2: scatter target_idx -> 1.0f (after prep's zeroing).
// ---------------------------------------------------------------------------
__global__ __launch_bounds__(256) void scatter_kernel(
        const int* __restrict__ idx, float* __restrict__ out2) {
    int i = blockIdx.x * 256 + threadIdx.x;
    if (i < N_TGT) out2[idx[i]] = 1.0f;
}

// ---------------------------------------------------------------------------
// Kernel 3: convert fea -> swizzled bf16 A strips; fp32 exist = fea.V[k]+eb;
//           keep[n*8+k] = (exist>0) | target. One wave per parent row.
// Grid: NROWS/4 blocks x 256 threads (4 waves).
// ---------------------------------------------------------------------------
__global__ __launch_bounds__(256) void convert_kernel(
        const float* __restrict__ fea, const float* __restrict__ target,
        float* __restrict__ out1, unsigned char* __restrict__ ws) {
    const float* V = (const float*)(ws + OFF_V);
    const float eb = *(const float*)(ws + OFF_EB);

    const int rowid = blockIdx.x * 4 + (threadIdx.x >> 6);   // 0..50047
    const int lane  = threadIdx.x & 63;
    const bool valid = rowid < N_PARENT;

    floatx4 f = (floatx4){0.f, 0.f, 0.f, 0.f};
    if (valid)
        f = __builtin_nontemporal_load(
                (const floatx4*)&fea[(size_t)rowid * C_IN + lane * 4]);

    float ex[8];
    #pragma unroll
    for (int k = 0; k < 8; ++k) {
        const float4 v = *(const float4*)&V[k * 256 + lane * 4];
        ex[k] = f[0] * v.x + f[1] * v.y + f[2] * v.z + f[3] * v.w;
    }

    // write swizzled bf16 A (zeros for pad rows)
    const unsigned long long pk =
          (unsigned long long)f2bf(f[0])
        | ((unsigned long long)f2bf(f[1]) << 16)
        | ((unsigned long long)f2bf(f[2]) << 32)
        | ((unsigned long long)f2bf(f[3]) << 48);
    const int strip = rowid >> 7, r = rowid & 127;
    const int t = lane >> 3, ch = (lane >> 1) & 3, half = lane & 1;
    const unsigned off = OFF_A + (unsigned)strip * 65536u + (unsigned)t * 8192u
                       + (unsigned)r * 64u + (unsigned)((ch ^ (r & 3)) << 4)
                       + (unsigned)(half * 8);
    *(unsigned long long*)(ws + off) = pk;

    // reduce over lane bits 3,4,5 (24 shfl), static 8-way select, then
    // reduce over lane bits 0,1,2 (3 shfl)
    #pragma unroll
    for (int m = 8; m < 64; m <<= 1)
        #pragma unroll
        for (int k = 0; k < 8; ++k) ex[k] += __shfl_xor(ex[k], m);

    const int ksel = lane >> 3;
    float v = ex[0];
    #pragma unroll
    for (int k = 1; k < 8; ++k) v = (ksel == k) ? ex[k] : v;
    #pragma unroll
    for (int m = 1; m < 8; m <<= 1) v += __shfl_xor(v, m);
    v += eb;

    if ((lane & 7) == 0 && valid) {
        const size_t o = (size_t)rowid * FANOUT + ksel;
        out1[o] = v;
        ws[OFF_KEEP + o] = ((v > 0.0f) || (target[o] != 0.0f)) ? 1 : 0;
    }
}

// ---------------------------------------------------------------------------
// Kernel 4: bf16 MFMA GEMM, 2-deep double-buffered BK=32 pipeline (T3-min):
// issue next tile's global_load_lds BEFORE current tile's ds_read+MFMA, one
// barrier per step. 32KB LDS -> 4 blocks/CU. Swizzled ds_read, operand-swapped
// MFMA for float4 stores, XCD-grouped mapping, nontemporal out0 stores.
// ---------------------------------------------------------------------------
__global__ __launch_bounds__(256, 4) void gemm_kernel(
        const float* __restrict__ b_up, const unsigned char* __restrict__ ws,
        float* __restrict__ out0) {
    __shared__ unsigned short As[2][4096];   // 8KB each: 128 rows x 32 cols
    __shared__ unsigned short Bs[2][4096];
    __shared__ unsigned char keeps[128];

    // XCD grouping: all 16 bn-blocks of one bm share bid&7 -> same XCD L2.
    const int bid = blockIdx.x;
    const int g = bid & 7, u = bid >> 3;
    const int tt = u >> 4, bn = u & 15;
    const int bm = g + 8 * tt;
    if (bm >= NSTRIP) return;              // 16 pad blocks idle

    const unsigned char* Abase = ws + OFF_A + (size_t)bm * 65536u;
    const unsigned char* Bbase = ws + OFF_B + (size_t)bn * 65536u;

    const int tid  = threadIdx.x;
    const int lane = tid & 63;
    const int wid  = tid >> 6;
    const int wr = wid >> 1, wc = wid & 1;    // 2x2 wave grid (64x64 each)
    const int llo = lane & 15, lhi = lane >> 4;

    if (tid < 128) {
        const int n = bm * 128 + tid;
        keeps[tid] = (n < N_PARENT) ? ws[OFF_KEEP + (size_t)n * FANOUT + (bn >> 1)] : 0;
    }

    floatx4 acc[4][4];
    #pragma unroll
    for (int a = 0; a < 4; ++a)
        #pragma unroll
        for (int b = 0; b < 4; ++b) acc[a][b] = (floatx4){0.f, 0.f, 0.f, 0.f};

    // prologue: stage t=0 into buffer 0
    gload_lds16(Abase + tid * 16,        (char*)As[0] + tid * 16);
    gload_lds16(Abase + 4096 + tid * 16, (char*)As[0] + 4096 + tid * 16);
    gload_lds16(Bbase + tid * 16,        (char*)Bs[0] + tid * 16);
    gload_lds16(Bbase + 4096 + tid * 16, (char*)Bs[0] + 4096 + tid * 16);
    __syncthreads();

    #pragma unroll
    for (int t = 0; t < 8; ++t) {
        const int cur = t & 1;
        if (t < 7) {   // issue next-tile loads BEFORE compute on current
            const unsigned o = (unsigned)(t + 1) * 8192u;
            gload_lds16(Abase + o + tid * 16,        (char*)As[cur ^ 1] + tid * 16);
            gload_lds16(Abase + o + 4096 + tid * 16, (char*)As[cur ^ 1] + 4096 + tid * 16);
            gload_lds16(Bbase + o + tid * 16,        (char*)Bs[cur ^ 1] + tid * 16);
            gload_lds16(Bbase + o + 4096 + tid * 16, (char*)Bs[cur ^ 1] + 4096 + tid * 16);
        }

        short8 af[4], bf[4];
        #pragma unroll
        for (int fm = 0; fm < 4; ++fm) {
            const int row = wr * 64 + fm * 16 + llo;
            const int ch = lhi ^ (row & 3);
            af[fm] = *(const short8*)((const char*)As[cur] + row * 64 + ch * 16);
        }
        #pragma unroll
        for (int fn = 0; fn < 4; ++fn) {
            const int row = wc * 64 + fn * 16 + llo;
            const int ch = lhi ^ (row & 3);
            bf[fn] = *(const short8*)((const char*)Bs[cur] + row * 64 + ch * 16);
        }
        // operand swap: D[j][m] so the 4 acc regs span 4 consecutive columns
        #pragma unroll
        for (int fm = 0; fm < 4; ++fm)
            #pragma unroll
            for (int fn = 0; fn < 4; ++fn)
                acc[fm][fn] = __builtin_amdgcn_mfma_f32_16x16x32_bf16(
                    bf[fn], af[fm], acc[fm][fn], 0, 0, 0);

        if (t < 7) __syncthreads();   // drains next-tile loads + LDS reads
    }

    // epilogue: masked nontemporal float4 stores (+b_up)
    const int j0 = bn * 128;
    #pragma unroll
    for (int fm = 0; fm < 4; ++fm) {
        const int row = wr * 64 + fm * 16 + llo;
        const int m = bm * 128 + row;
        if (m >= N_PARENT) continue;
        const bool kp = keeps[row] != 0;
        #pragma unroll
        for (int fn = 0; fn < 4; ++fn) {
            const int j = j0 + wc * 64 + fn * 16 + lhi * 4;
            const float4 bv = *(const float4*)&b_up[j & 255];
            const floatx4 a = acc[fm][fn];
            floatx4 o;
            o[0] = kp ? a[0] + bv.x : 0.0f;
            o[1] = kp ? a[1] + bv.y : 0.0f;
            o[2] = kp ? a[2] + bv.z : 0.0f;
            o[3] = kp ? a[3] + bv.w : 0.0f;
            __builtin_nontemporal_store(o, (floatx4*)&out0[(size_t)m * NCOL + j]);
        }
    }
}

// ---------------------------------------------------------------------------
extern "C" void kernel_launch(void* const* d_in, const int* in_sizes, int n_in,
                              void* d_out, int out_size, void* d_ws, size_t ws_size,
                              hipStream_t stream) {
    const float* fea   = (const float*)d_in[0];
    const float* W_up  = (const float*)d_in[1];
    const float* b_up  = (const float*)d_in[2];
    const float* W_cls = (const float*)d_in[3];
    const float* b_cls = (const float*)d_in[4];
    const int*   tidx  = (const int*)d_in[5];

    float* out0 = (float*)d_out;                       // fea_pruned [400000,256]
    float* out1 = out0 + (size_t)N_UP * C_OUT;         // exist      [400000]
    float* out2 = out1 + N_UP;                         // target     [400000]
    unsigned char* ws = (unsigned char*)d_ws;          // needs ~27.1 MB

    prep_kernel<<<2048, 256, 0, stream>>>(W_up, b_up, W_cls, b_cls, ws, out2);
    scatter_kernel<<<(N_TGT + 255) / 256, 256, 0, stream>>>(tidx, out2);
    convert_kernel<<<NROWS / 4, 256, 0, stream>>>(fea, out2, out1, ws);
    gemm_kernel<<<392 * 16, 256, 0, stream>>>(b_up, ws, out0);
}

// Round 5
// 148.689 us; speedup vs baseline: 1.0161x; 1.0161x over previous
//
#include <hip/hip_runtime.h>
#include <hip/hip_bf16.h>

// Problem constants (from reference setup_inputs)
#define N_PARENT 50000
#define C_IN     256
#define C_OUT    256
#define FANOUT   8
#define N_TGT    200000
#define N_UP     (N_PARENT * FANOUT)   // 400000 upsampled rows
#define NCOL     (FANOUT * C_OUT)      // 2048 = fused (k,d) GEMM-N
#define NSTRIP   391                   // ceil(50000/128) M-strips of 128 rows
#define NROWS    (NSTRIP * 128)        // 50048 (rows 50000..50047 are zero pad)

// Workspace layout (~27.1 MB)
//  A strips: bf16 [strip][t=0..7][8KB], 391*64KB   (t = 32-col K-step)
//  B tiles:  bf16 [bn][t=0..7][8KB], 16*64KB = 1MB
// Within an 8KB (128 rows x 32 cols bf16) block:
//   byte = r*64 + ((ch ^ (r&3))<<4) + lo   where ch = 16B chunk (8 bf16), lo<16
#define OFF_A    0u
#define OFF_B    (NSTRIP * 65536u)              // 25,624,576
#define OFF_V    (OFF_B + 16u * 65536u)         // float V[8][256]
#define OFF_EB   (OFF_V + 8192u)                // float ebias
#define OFF_KEEP (OFF_EB + 256u)                // uint8 keep[N_UP]

typedef __attribute__((ext_vector_type(8))) short short8;
typedef __attribute__((ext_vector_type(4))) float floatx4;

static __device__ __forceinline__ unsigned short f2bf(float f) {
    return __builtin_bit_cast(unsigned short, __float2bfloat16(f));
}

static __device__ __forceinline__ void gload_lds16(const void* gsrc, void* ldsdst) {
    __builtin_amdgcn_global_load_lds(
        (const __attribute__((address_space(1))) unsigned int*)gsrc,
        (__attribute__((address_space(3))) unsigned int*)ldsdst, 16, 0, 0);
}

#define SCHED_BAR() __builtin_amdgcn_sched_barrier(0)
#define SBAR()      __builtin_amdgcn_s_barrier()

// ---------------------------------------------------------------------------
// Kernel 1: build swizzled bf16 B tiles + V[k][c] = W_up[k] @ W_cls + ebias,
//           and zero the target output (fused zero pass).
// Grid: 2048 blocks (= k*256 + c), 256 threads (= d). Reads coalesced over d.
// ---------------------------------------------------------------------------
__global__ __launch_bounds__(256) void prep_kernel(
        const float* __restrict__ W_up, const float* __restrict__ b_up,
        const float* __restrict__ W_cls, const float* __restrict__ b_cls,
        unsigned char* __restrict__ ws, float* __restrict__ out2) {
    __shared__ float sm[4];
    const int bid = blockIdx.x;
    const int k = bid >> 8, c = bid & 255;
    const int d = threadIdx.x;

    // fused zero of out2 (100000 float4 across 2048 blocks, 49 each)
    if (d < 49) {
        const int i4 = bid * 49 + d;
        if (i4 < N_UP / 4)
            *(floatx4*)&out2[i4 * 4] = (floatx4){0.f, 0.f, 0.f, 0.f};
    }

    const float w = W_up[((k * 256 + c) * 256) + d];      // coalesced over d
    // B^T element: row j = k*256+d -> (bn = j>>7, jr = j&127), col c
    const int bn = (k << 1) | (d >> 7);
    const int jr = d & 127;
    const int t  = c >> 5;
    const int ch = (c >> 3) & 3;
    const int e  = c & 7;
    const unsigned off = OFF_B + (unsigned)bn * 65536u + (unsigned)t * 8192u
                       + (unsigned)jr * 64u + (unsigned)((ch ^ (jr & 3)) << 4)
                       + (unsigned)(e << 1);
    *(unsigned short*)(ws + off) = f2bf(w);

    // V[k][c] = sum_d w * W_cls[d]  (fp32 tree reduce)
    float p = w * W_cls[d];
    #pragma unroll
    for (int m = 1; m < 64; m <<= 1) p += __shfl_xor(p, m);
    if ((d & 63) == 0) sm[d >> 6] = p;
    __syncthreads();
    if (d == 0)
        ((float*)(ws + OFF_V))[k * 256 + c] = sm[0] + sm[1] + sm[2] + sm[3];

    if (bid == 0) {   // uniform branch: whole block participates
        __syncthreads();
        float q = b_up[d] * W_cls[d];
        #pragma unroll
        for (int m = 1; m < 64; m <<= 1) q += __shfl_xor(q, m);
        if ((d & 63) == 0) sm[d >> 6] = q;
        __syncthreads();
        if (d == 0)
            *((float*)(ws + OFF_EB)) = sm[0] + sm[1] + sm[2] + sm[3] + b_cls[0];
    }
}

// ---------------------------------------------------------------------------
// Kernel 2: scatter target_idx -> 1.0f (after prep's zeroing).
// ---------------------------------------------------------------------------
__global__ __launch_bounds__(256) void scatter_kernel(
        const int* __restrict__ idx, float* __restrict__ out2) {
    int i = blockIdx.x * 256 + threadIdx.x;
    if (i < N_TGT) out2[idx[i]] = 1.0f;
}

// ---------------------------------------------------------------------------
// Kernel 3: convert fea -> swizzled bf16 A strips; fp32 exist = fea.V[k]+eb;
//           keep[n*8+k] = (exist>0) | target. One wave per parent row.
// Grid: NROWS/4 blocks x 256 threads (4 waves).
// ---------------------------------------------------------------------------
__global__ __launch_bounds__(256) void convert_kernel(
        const float* __restrict__ fea, const float* __restrict__ target,
        float* __restrict__ out1, unsigned char* __restrict__ ws) {
    const float* V = (const float*)(ws + OFF_V);
    const float eb = *(const float*)(ws + OFF_EB);

    const int rowid = blockIdx.x * 4 + (threadIdx.x >> 6);   // 0..50047
    const int lane  = threadIdx.x & 63;
    const bool valid = rowid < N_PARENT;

    floatx4 f = (floatx4){0.f, 0.f, 0.f, 0.f};
    if (valid)
        f = __builtin_nontemporal_load(
                (const floatx4*)&fea[(size_t)rowid * C_IN + lane * 4]);

    float ex[8];
    #pragma unroll
    for (int k = 0; k < 8; ++k) {
        const float4 v = *(const float4*)&V[k * 256 + lane * 4];
        ex[k] = f[0] * v.x + f[1] * v.y + f[2] * v.z + f[3] * v.w;
    }

    // write swizzled bf16 A (zeros for pad rows)
    const unsigned long long pk =
          (unsigned long long)f2bf(f[0])
        | ((unsigned long long)f2bf(f[1]) << 16)
        | ((unsigned long long)f2bf(f[2]) << 32)
        | ((unsigned long long)f2bf(f[3]) << 48);
    const int strip = rowid >> 7, r = rowid & 127;
    const int t = lane >> 3, ch = (lane >> 1) & 3, half = lane & 1;
    const unsigned off = OFF_A + (unsigned)strip * 65536u + (unsigned)t * 8192u
                       + (unsigned)r * 64u + (unsigned)((ch ^ (r & 3)) << 4)
                       + (unsigned)(half * 8);
    *(unsigned long long*)(ws + off) = pk;

    // reduce over lane bits 3,4,5 (24 shfl), static 8-way select, then
    // reduce over lane bits 0,1,2 (3 shfl)
    #pragma unroll
    for (int m = 8; m < 64; m <<= 1)
        #pragma unroll
        for (int k = 0; k < 8; ++k) ex[k] += __shfl_xor(ex[k], m);

    const int ksel = lane >> 3;
    float v = ex[0];
    #pragma unroll
    for (int k = 1; k < 8; ++k) v = (ksel == k) ? ex[k] : v;
    #pragma unroll
    for (int m = 1; m < 8; m <<= 1) v += __shfl_xor(v, m);
    v += eb;

    if ((lane & 7) == 0 && valid) {
        const size_t o = (size_t)rowid * FANOUT + ksel;
        out1[o] = v;
        ws[OFF_KEEP + o] = ((v > 0.0f) || (target[o] != 0.0f)) ? 1 : 0;
    }
}

// ---------------------------------------------------------------------------
// Kernel 4: bf16 MFMA GEMM with T4 counted-vmcnt 2-deep pipeline:
//   prologue stages tiles 0,1; step t: vmcnt(4) [tile t done, t+1 in flight
//   ACROSS the barrier], raw s_barrier, ds_read frags, lgkmcnt(0)+s_barrier
//   [buf reusable], issue tile t+2, 16 MFMA. No vmcnt(0) drain in the loop.
// 32KB LDS -> 4 blocks/CU. Swizzled ds_read, operand-swapped MFMA, XCD-grouped
// mapping, nontemporal out0 stores.
// ---------------------------------------------------------------------------
__global__ __launch_bounds__(256, 4) void gemm_kernel(
        const float* __restrict__ b_up, const unsigned char* __restrict__ ws,
        float* __restrict__ out0) {
    __shared__ unsigned short As[2][4096];   // 8KB each: 128 rows x 32 cols
    __shared__ unsigned short Bs[2][4096];
    __shared__ unsigned char keeps[128];

    // XCD grouping: all 16 bn-blocks of one bm share bid&7 -> same XCD L2.
    const int bid = blockIdx.x;
    const int g = bid & 7, u = bid >> 3;
    const int tt = u >> 4, bn = u & 15;
    const int bm = g + 8 * tt;
    if (bm >= NSTRIP) return;              // 16 pad blocks idle

    const unsigned char* Abase = ws + OFF_A + (size_t)bm * 65536u;
    const unsigned char* Bbase = ws + OFF_B + (size_t)bn * 65536u;

    const int tid  = threadIdx.x;
    const int lane = tid & 63;
    const int wid  = tid >> 6;
    const int wr = wid >> 1, wc = wid & 1;    // 2x2 wave grid (64x64 each)
    const int llo = lane & 15, lhi = lane >> 4;

    if (tid < 128) {
        const int n = bm * 128 + tid;
        keeps[tid] = (n < N_PARENT) ? ws[OFF_KEEP + (size_t)n * FANOUT + (bn >> 1)] : 0;
    }

    floatx4 acc[4][4];
    #pragma unroll
    for (int a = 0; a < 4; ++a)
        #pragma unroll
        for (int b = 0; b < 4; ++b) acc[a][b] = (floatx4){0.f, 0.f, 0.f, 0.f};

    // prologue: stage tiles 0 and 1 (4 gloads per thread each)
    #pragma unroll
    for (int t0 = 0; t0 < 2; ++t0) {
        const unsigned o = (unsigned)t0 * 8192u;
        gload_lds16(Abase + o + tid * 16,        (char*)As[t0] + tid * 16);
        gload_lds16(Abase + o + 4096 + tid * 16, (char*)As[t0] + 4096 + tid * 16);
        gload_lds16(Bbase + o + tid * 16,        (char*)Bs[t0] + tid * 16);
        gload_lds16(Bbase + o + 4096 + tid * 16, (char*)Bs[t0] + 4096 + tid * 16);
    }

    #pragma unroll
    for (int t = 0; t < 8; ++t) {
        const int cur = t & 1;

        // wait for tile t's 4 gloads (leave t+1's in flight), then barrier
        if (t < 7) asm volatile("s_waitcnt vmcnt(4)" ::: "memory");
        else       asm volatile("s_waitcnt vmcnt(0)" ::: "memory");
        SCHED_BAR();
        SBAR();
        SCHED_BAR();

        // ds_read fragments from buf[cur] (swizzled)
        short8 af[4], bf[4];
        #pragma unroll
        for (int fm = 0; fm < 4; ++fm) {
            const int row = wr * 64 + fm * 16 + llo;
            const int ch = lhi ^ (row & 3);
            af[fm] = *(const short8*)((const char*)As[cur] + row * 64 + ch * 16);
        }
        #pragma unroll
        for (int fn = 0; fn < 4; ++fn) {
            const int row = wc * 64 + fn * 16 + llo;
            const int ch = lhi ^ (row & 3);
            bf[fn] = *(const short8*)((const char*)Bs[cur] + row * 64 + ch * 16);
        }

        // all reads landed -> barrier -> buf[cur] is safe to overwrite
        asm volatile("s_waitcnt lgkmcnt(0)" ::: "memory");
        SCHED_BAR();
        SBAR();
        SCHED_BAR();

        if (t < 6) {   // issue tile t+2 into buf[cur]; covered by MFMA + next step
            const unsigned o = (unsigned)(t + 2) * 8192u;
            gload_lds16(Abase + o + tid * 16,        (char*)As[cur] + tid * 16);
            gload_lds16(Abase + o + 4096 + tid * 16, (char*)As[cur] + 4096 + tid * 16);
            gload_lds16(Bbase + o + tid * 16,        (char*)Bs[cur] + tid * 16);
            gload_lds16(Bbase + o + 4096 + tid * 16, (char*)Bs[cur] + 4096 + tid * 16);
        }

        // operand swap: D[j][m] so the 4 acc regs span 4 consecutive columns
        #pragma unroll
        for (int fm = 0; fm < 4; ++fm)
            #pragma unroll
            for (int fn = 0; fn < 4; ++fn)
                acc[fm][fn] = __builtin_amdgcn_mfma_f32_16x16x32_bf16(
                    bf[fn], af[fm], acc[fm][fn], 0, 0, 0);
    }

    // epilogue: masked nontemporal float4 stores (+b_up)
    const int j0 = bn * 128;
    #pragma unroll
    for (int fm = 0; fm < 4; ++fm) {
        const int row = wr * 64 + fm * 16 + llo;
        const int m = bm * 128 + row;
        if (m >= N_PARENT) continue;
        const bool kp = keeps[row] != 0;
        #pragma unroll
        for (int fn = 0; fn < 4; ++fn) {
            const int j = j0 + wc * 64 + fn * 16 + lhi * 4;
            const float4 bv = *(const float4*)&b_up[j & 255];
            const floatx4 a = acc[fm][fn];
            floatx4 o;
            o[0] = kp ? a[0] + bv.x : 0.0f;
            o[1] = kp ? a[1] + bv.y : 0.0f;
            o[2] = kp ? a[2] + bv.z : 0.0f;
            o[3] = kp ? a[3] + bv.w : 0.0f;
            __builtin_nontemporal_store(o, (floatx4*)&out0[(size_t)m * NCOL + j]);
        }
    }
}

// ---------------------------------------------------------------------------
extern "C" void kernel_launch(void* const* d_in, const int* in_sizes, int n_in,
                              void* d_out, int out_size, void* d_ws, size_t ws_size,
                              hipStream_t stream) {
    const float* fea   = (const float*)d_in[0];
    const float* W_up  = (const float*)d_in[1];
    const float* b_up  = (const float*)d_in[2];
    const float* W_cls = (const float*)d_in[3];
    const float* b_cls = (const float*)d_in[4];
    const int*   tidx  = (const int*)d_in[5];

    float* out0 = (float*)d_out;                       // fea_pruned [400000,256]
    float* out1 = out0 + (size_t)N_UP * C_OUT;         // exist      [400000]
    float* out2 = out1 + N_UP;                         // target     [400000]
    unsigned char* ws = (unsigned char*)d_ws;          // needs ~27.1 MB

    prep_kernel<<<2048, 256, 0, stream>>>(W_up, b_up, W_cls, b_cls, ws, out2);
    scatter_kernel<<<(N_TGT + 255) / 256, 256, 0, stream>>>(tidx, out2);
    convert_kernel<<<NROWS / 4, 256, 0, stream>>>(fea, out2, out1, ws);
    gemm_kernel<<<392 * 16, 256, 0, stream>>>(b_up, ws, out0);
}